// Round 4
// baseline (247.489 us; speedup 1.0000x reference)
//
#include <hip/hip_runtime.h>

#define HEADS  16
#define DH     64
#define SEQ    2048
#define NBATCH 2
#define EMB    1024
#define MTOT   (NBATCH * SEQ)  // 4096

// Q pre-scale: 1/sqrt(1024) * log2(e)  (softmax done in base 2)
#define QSCALE 0.045084220027780106f

typedef short  s16x8 __attribute__((ext_vector_type(8)));
typedef float  f32x4 __attribute__((ext_vector_type(4)));
typedef unsigned short u16;
typedef unsigned short u16x4 __attribute__((ext_vector_type(4)));

__device__ __forceinline__ u16 f2bf(float f) {
  unsigned u = __builtin_bit_cast(unsigned, f);
  u += 0x7fffu + ((u >> 16) & 1u);   // RNE
  return (u16)(u >> 16);
}

// async global->LDS, 16B per lane; lds ptr wave-uniform base (HW adds lane*16)
__device__ __forceinline__ void gll16(const u16* g, u16* l) {
  __builtin_amdgcn_global_load_lds(
      (const __attribute__((address_space(1))) unsigned int*)g,
      (__attribute__((address_space(3))) unsigned int*)l, 16, 0, 0);
}

// ---------------- fp32 -> bf16 bulk convert (x) ----------------
__global__ void cvt_x_kernel(const float* __restrict__ x, u16* __restrict__ xb) {
  int i = (blockIdx.x * 256 + threadIdx.x) * 4;
  float4 v = *(const float4*)(x + i);
  u16x4 o;
  o.x = f2bf(v.x); o.y = f2bf(v.y); o.z = f2bf(v.z); o.w = f2bf(v.w);
  *(u16x4*)(xb + i) = o;
}

// ---------------- weight transpose + convert: Wt[n][k] = bf16(W[k][n]) ----------------
__global__ void cvt_wt_kernel(const float* __restrict__ Wq, const float* __restrict__ Wk,
                              const float* __restrict__ Wv, const float* __restrict__ Wo,
                              u16* __restrict__ Wqt, u16* __restrict__ Wkt,
                              u16* __restrict__ Wvt, u16* __restrict__ Wot) {
  __shared__ float tile[32][33];
  const float* W; u16* T;
  switch (blockIdx.z) {
    case 0:  W = Wq; T = Wqt; break;
    case 1:  W = Wk; T = Wkt; break;
    case 2:  W = Wv; T = Wvt; break;
    default: W = Wo; T = Wot; break;
  }
  int n0 = blockIdx.x * 32, k0 = blockIdx.y * 32;
  int tx = threadIdx.x, ty = threadIdx.y;
#pragma unroll
  for (int r = 0; r < 32; r += 8)
    tile[ty + r][tx] = W[(size_t)(k0 + ty + r) * EMB + n0 + tx];
  __syncthreads();
#pragma unroll
  for (int r = 0; r < 32; r += 8)
    T[(size_t)(n0 + ty + r) * EMB + k0 + tx] = f2bf(tile[tx][ty + r]);
}

// ---------------- QKV GEMM: BM=128, BN=128, BK=64, 256 thr (2x2 waves) ----------------
// z: 0 -> Q (scaled, mode s-major), 1 -> K (s-major), 2 -> V (transposed d-major)
__global__ __launch_bounds__(256) void gemm_qkv(const u16* __restrict__ A,
                                                const u16* __restrict__ Wqt, const u16* __restrict__ Wkt,
                                                const u16* __restrict__ Wvt,
                                                const float* __restrict__ bq, const float* __restrict__ bk,
                                                const float* __restrict__ bv,
                                                u16* __restrict__ Qb, u16* __restrict__ Kb,
                                                u16* __restrict__ Vtb) {
  __shared__ __align__(16) u16 As[128 * 64];
  __shared__ __align__(16) u16 Bs[128 * 64];
  const u16* Bt; const float* bias; u16* out; const int mode = blockIdx.z;
  switch (mode) {
    case 0:  Bt = Wqt; bias = bq; out = Qb;  break;
    case 1:  Bt = Wkt; bias = bk; out = Kb;  break;
    default: Bt = Wvt; bias = bv; out = Vtb; break;
  }
  const int tid = threadIdx.x, lane = tid & 63, w = tid >> 6;
  const int wm = w >> 1, wn = w & 1;
  const int lr = lane & 15, lq = lane >> 4;
  const int m0 = blockIdx.y * 128, n0 = blockIdx.x * 128;
  f32x4 acc[4][4];
#pragma unroll
  for (int i = 0; i < 4; i++)
#pragma unroll
    for (int j = 0; j < 4; j++)
      acc[i][j] = (f32x4){0.f, 0.f, 0.f, 0.f};

  for (int k0 = 0; k0 < EMB; k0 += 64) {
    __syncthreads();
#pragma unroll
    for (int j = 0; j < 4; j++) {
      int c = tid + 256 * j;
      gll16(&A[(size_t)(m0 + (c >> 3)) * EMB + k0 + (c & 7) * 8],
            &As[(w * 64 + 256 * j) * 8]);
    }
#pragma unroll
    for (int j = 0; j < 4; j++) {
      int c = tid + 256 * j;
      gll16(&Bt[(size_t)(n0 + (c >> 3)) * EMB + k0 + (c & 7) * 8],
            &Bs[(w * 64 + 256 * j) * 8]);
    }
    __syncthreads();
#pragma unroll
    for (int kk = 0; kk < 64; kk += 32) {
      s16x8 af[4], bf[4];
#pragma unroll
      for (int i = 0; i < 4; i++)
        af[i] = *(const s16x8*)&As[(wm * 64 + i * 16 + lr) * 64 + kk + lq * 8];
#pragma unroll
      for (int j = 0; j < 4; j++)
        bf[j] = *(const s16x8*)&Bs[(wn * 64 + j * 16 + lr) * 64 + kk + lq * 8];
#pragma unroll
      for (int i = 0; i < 4; i++)
#pragma unroll
        for (int j = 0; j < 4; j++)
          acc[i][j] = __builtin_amdgcn_mfma_f32_16x16x32_bf16(af[i], bf[j], acc[i][j], 0, 0, 0);
    }
  }
#pragma unroll
  for (int i = 0; i < 4; i++) {
#pragma unroll
    for (int j = 0; j < 4; j++) {
      int col   = n0 + wn * 64 + j * 16 + lr;
      int mbase = m0 + wm * 64 + i * 16 + lq * 4;
      float bv_ = bias[col];
      int h = col >> 6, d = col & 63;
      if (mode == 0) {
#pragma unroll
        for (int r = 0; r < 4; r++) {
          int m = mbase + r, b = m >> 11, s = m & (SEQ - 1);
          out[((size_t)(b * HEADS + h) * SEQ + s) * DH + d] = f2bf((acc[i][j][r] + bv_) * QSCALE);
        }
      } else if (mode == 1) {
#pragma unroll
        for (int r = 0; r < 4; r++) {
          int m = mbase + r, b = m >> 11, s = m & (SEQ - 1);
          out[((size_t)(b * HEADS + h) * SEQ + s) * DH + d] = f2bf(acc[i][j][r] + bv_);
        }
      } else {
        int b = mbase >> 11, s = mbase & (SEQ - 1);
        u16x4 pk;
        pk.x = f2bf(acc[i][j][0] + bv_);
        pk.y = f2bf(acc[i][j][1] + bv_);
        pk.z = f2bf(acc[i][j][2] + bv_);
        pk.w = f2bf(acc[i][j][3] + bv_);
        *(u16x4*)&out[((size_t)(b * HEADS + h) * DH + d) * SEQ + s] = pk;
      }
    }
  }
}

// ---------------- out-proj GEMM: BM=64, BN=128, BK=64, 256 thr (1x4 waves) ----------------
__global__ __launch_bounds__(256) void gemm_out(const u16* __restrict__ A, const u16* __restrict__ Bt,
                                                const float* __restrict__ bias, float* __restrict__ out) {
  __shared__ __align__(16) u16 As[64 * 64];
  __shared__ __align__(16) u16 Bs[128 * 64];
  const int tid = threadIdx.x, lane = tid & 63, w = tid >> 6;
  const int lr = lane & 15, lq = lane >> 4;
  const int m0 = blockIdx.y * 64, n0 = blockIdx.x * 128;
  f32x4 acc[4][2];
#pragma unroll
  for (int i = 0; i < 4; i++)
#pragma unroll
    for (int j = 0; j < 2; j++)
      acc[i][j] = (f32x4){0.f, 0.f, 0.f, 0.f};

  for (int k0 = 0; k0 < EMB; k0 += 64) {
    __syncthreads();
#pragma unroll
    for (int j = 0; j < 2; j++) {
      int c = tid + 256 * j;
      gll16(&A[(size_t)(m0 + (c >> 3)) * EMB + k0 + (c & 7) * 8],
            &As[(w * 64 + 256 * j) * 8]);
    }
#pragma unroll
    for (int j = 0; j < 4; j++) {
      int c = tid + 256 * j;
      gll16(&Bt[(size_t)(n0 + (c >> 3)) * EMB + k0 + (c & 7) * 8],
            &Bs[(w * 64 + 256 * j) * 8]);
    }
    __syncthreads();
#pragma unroll
    for (int kk = 0; kk < 64; kk += 32) {
      s16x8 af[4], bf[2];
#pragma unroll
      for (int i = 0; i < 4; i++)
        af[i] = *(const s16x8*)&As[(i * 16 + lr) * 64 + kk + lq * 8];
#pragma unroll
      for (int j = 0; j < 2; j++)
        bf[j] = *(const s16x8*)&Bs[(w * 32 + j * 16 + lr) * 64 + kk + lq * 8];
#pragma unroll
      for (int i = 0; i < 4; i++)
#pragma unroll
        for (int j = 0; j < 2; j++)
          acc[i][j] = __builtin_amdgcn_mfma_f32_16x16x32_bf16(af[i], bf[j], acc[i][j], 0, 0, 0);
    }
  }
#pragma unroll
  for (int i = 0; i < 4; i++) {
#pragma unroll
    for (int j = 0; j < 2; j++) {
      int col   = n0 + w * 32 + j * 16 + lr;
      int mbase = m0 + i * 16 + lq * 4;
      float bv_ = bias[col];
#pragma unroll
      for (int r = 0; r < 4; r++)
        out[(size_t)(mbase + r) * EMB + col] = acc[i][j][r] + bv_;
    }
  }
}

// ---------------- fused causal attention, paired q-tiles, 128-key tiles ----------------
// grid (16, B*H); 512 thr = 8 waves. waves 0-3: q-tile bx, waves 4-7: q-tile 31-bx.
// Q pre-scaled by 1/32*log2(e); softmax in base 2 (v_exp_f32 native).
__global__ __launch_bounds__(512) void attn_fwd(const u16* __restrict__ Q,
                                                const u16* __restrict__ Kg,
                                                const u16* __restrict__ Vt,
                                                u16* __restrict__ O) {
  __shared__ __align__(16) u16 Ks[128 * 80];     // [key][d], stride 80
  __shared__ __align__(16) u16 Vs[64 * 136];     // [d][key], stride 136
  __shared__ __align__(16) u16 Ps[8][16 * 72];   // per-wave P half-tile [qrow][key64]
  const int tid = threadIdx.x, lane = tid & 63, w = tid >> 6;
  const int lr = lane & 15, lq = lane >> 4;
  const int bh = blockIdx.y, bx = blockIdx.x;
  const int qtA = bx, qtB = 31 - bx;             // qtB >= qtA
  const int myqt = (w < 4) ? qtA : qtB;
  const int rowoff = (w & 3) * 16;
  const int qrow_g = myqt * 64 + rowoff + lq * 4;   // + r
  const size_t qkbase = (size_t)bh * SEQ * DH;
  const size_t vbase  = (size_t)bh * DH * SEQ;
  const u16* kgp = Kg + qkbase;
  const u16* vtp = Vt + vbase;

  s16x8 qf0, qf1;
  {
    const u16* qrow = Q + qkbase + (size_t)(myqt * 64 + rowoff + lr) * DH;
    qf0 = *(const s16x8*)&qrow[lq * 8];
    qf1 = *(const s16x8*)&qrow[32 + lq * 8];
  }
  f32x4 o[4];
#pragma unroll
  for (int t = 0; t < 4; t++) o[t] = (f32x4){0.f, 0.f, 0.f, 0.f};
  float mrow[4] = {-3e38f, -3e38f, -3e38f, -3e38f};
  float lsum[4] = {0.f, 0.f, 0.f, 0.f};

  // staging: 512 thr, 2x16B K-chunks + 2x16B V-chunks each (128-key tile = 32 KB)
  const int krow = tid >> 3, koff = (tid & 7) * 8;    // K rows 0..63 (+64 second chunk)
  const int vd   = tid >> 4, voff = (tid & 15) * 8;   // V d 0..31 (+32 second chunk)
  s16x8 kr0 = *(const s16x8*)&kgp[(size_t)krow * DH + koff];
  s16x8 kr1 = *(const s16x8*)&kgp[(size_t)(64 + krow) * DH + koff];
  s16x8 vr0 = *(const s16x8*)&vtp[(size_t)vd * SEQ + voff];
  s16x8 vr1 = *(const s16x8*)&vtp[(size_t)(vd + 32) * SEQ + voff];

  const int nkt2  = (qtB >> 1) + 1;
  const int mylast = myqt >> 1;
  for (int kt2 = 0; kt2 < nkt2; ++kt2) {
    const int kb = kt2 * 128;
    __syncthreads();   // previous iteration's LDS readers done
    *(s16x8*)&Ks[krow * 80 + koff]        = kr0;
    *(s16x8*)&Ks[(krow + 64) * 80 + koff] = kr1;
    *(s16x8*)&Vs[vd * 136 + voff]         = vr0;
    *(s16x8*)&Vs[(vd + 32) * 136 + voff]  = vr1;
    __syncthreads();
    if (kt2 + 1 < nkt2) {  // register prefetch of next 128-key tile
      int nb = kb + 128;
      kr0 = *(const s16x8*)&kgp[(size_t)(nb + krow) * DH + koff];
      kr1 = *(const s16x8*)&kgp[(size_t)(nb + 64 + krow) * DH + koff];
      vr0 = *(const s16x8*)&vtp[(size_t)vd * SEQ + nb + voff];
      vr1 = *(const s16x8*)&vtp[(size_t)(vd + 32) * SEQ + nb + voff];
    }
    if (kt2 > mylast) continue;  // wave-uniform; barriers stay in sync (top of loop)

    // S = Q @ K^T over 128 keys (scores already in log2 domain via Q pre-scale)
    f32x4 sc[8];
#pragma unroll
    for (int t = 0; t < 8; t++) {
      s16x8 kf0 = *(const s16x8*)&Ks[(t * 16 + lr) * 80 + lq * 8];
      s16x8 kf1 = *(const s16x8*)&Ks[(t * 16 + lr) * 80 + 32 + lq * 8];
      f32x4 z = (f32x4){0.f, 0.f, 0.f, 0.f};
      z = __builtin_amdgcn_mfma_f32_16x16x32_bf16(qf0, kf0, z, 0, 0, 0);
      z = __builtin_amdgcn_mfma_f32_16x16x32_bf16(qf1, kf1, z, 0, 0, 0);
      sc[t] = z;
    }

    const bool lastt = (kt2 == mylast);
    float rmax[4], rsum[4], alpha[4];
#pragma unroll
    for (int r = 0; r < 4; r++) {
      float mx = -3e38f;
#pragma unroll
      for (int t = 0; t < 8; t++) {
        float s = sc[t][r];
        if (lastt && (kb + t * 16 + lr) > (qrow_g + r)) { s = -1e9f; sc[t][r] = s; }
        mx = fmaxf(mx, s);
      }
      rmax[r] = mx;
    }
#pragma unroll
    for (int off = 1; off < 16; off <<= 1)
#pragma unroll
      for (int r = 0; r < 4; r++) rmax[r] = fmaxf(rmax[r], __shfl_xor(rmax[r], off));
#pragma unroll
    for (int r = 0; r < 4; r++) {
      float mnew = fmaxf(mrow[r], rmax[r]);
      alpha[r] = __builtin_amdgcn_exp2f(mrow[r] - mnew);
      mrow[r] = mnew;
      float sum = 0.f;
#pragma unroll
      for (int t = 0; t < 8; t++) {
        float p = __builtin_amdgcn_exp2f(sc[t][r] - mnew);
        sc[t][r] = p;
        sum += p;
      }
      rsum[r] = sum;
    }
#pragma unroll
    for (int off = 1; off < 16; off <<= 1)
#pragma unroll
      for (int r = 0; r < 4; r++) rsum[r] += __shfl_xor(rsum[r], off);
#pragma unroll
    for (int r = 0; r < 4; r++) {
      lsum[r] = lsum[r] * alpha[r] + rsum[r];
#pragma unroll
      for (int t = 0; t < 4; t++) o[t][r] *= alpha[r];
    }

    // P -> LDS (per-wave, barrier-free) and PV, in two 64-key halves
    u16* pw = &Ps[w][0];
#pragma unroll
    for (int h = 0; h < 2; h++) {
#pragma unroll
      for (int t = 0; t < 4; t++)
#pragma unroll
        for (int r = 0; r < 4; r++)
          pw[(lq * 4 + r) * 72 + t * 16 + lr] = f2bf(sc[h * 4 + t][r]);
#pragma unroll
      for (int kc = 0; kc < 2; kc++) {
        s16x8 pf = *(const s16x8*)&pw[lr * 72 + kc * 32 + lq * 8];
#pragma unroll
        for (int t = 0; t < 4; t++) {
          s16x8 vf = *(const s16x8*)&Vs[(t * 16 + lr) * 136 + h * 64 + kc * 32 + lq * 8];
          o[t] = __builtin_amdgcn_mfma_f32_16x16x32_bf16(pf, vf, o[t], 0, 0, 0);
        }
      }
    }
  }

  // epilogue: O[m][h*64+d] bf16
  const int b = bh >> 4, hh = bh & 15;
  float inv[4];
#pragma unroll
  for (int r = 0; r < 4; r++) inv[r] = __builtin_amdgcn_rcpf(lsum[r]);
#pragma unroll
  for (int t = 0; t < 4; t++) {
#pragma unroll
    for (int r = 0; r < 4; r++) {
      int m = b * SEQ + myqt * 64 + rowoff + lq * 4 + r;
      O[(size_t)m * EMB + hh * 64 + t * 16 + lr] = f2bf(o[t][r] * inv[r]);
    }
  }
}

extern "C" void kernel_launch(void* const* d_in, const int* in_sizes, int n_in,
                              void* d_out, int out_size, void* d_ws, size_t ws_size,
                              hipStream_t stream) {
  const float* x  = (const float*)d_in[0];
  const float* Wq = (const float*)d_in[2];
  const float* bq = (const float*)d_in[3];
  const float* Wk = (const float*)d_in[4];
  const float* bk = (const float*)d_in[5];
  const float* Wv = (const float*)d_in[6];
  const float* bv = (const float*)d_in[7];
  const float* Wo = (const float*)d_in[8];
  const float* bo = (const float*)d_in[9];

  char* ws = (char*)d_ws;
  const size_t MB = 1024 * 1024;
  u16* Qb  = (u16*)(ws + 0 * MB);    // [B][H][S][Dh] bf16 (pre-scaled)
  u16* Kb  = (u16*)(ws + 8 * MB);    // [B][H][S][Dh] bf16
  u16* Vtb = (u16*)(ws + 16 * MB);   // [B][H][Dh][S] bf16
  u16* xb  = (u16*)(ws + 24 * MB);   // [M][E] bf16
  u16* Ob  = xb;                     // alias: xb dead after QKV GEMMs
  u16* Wqt = (u16*)(ws + 32 * MB);
  u16* Wkt = (u16*)(ws + 34 * MB);
  u16* Wvt = (u16*)(ws + 36 * MB);
  u16* Wot = (u16*)(ws + 38 * MB);

  cvt_x_kernel<<<(MTOT * EMB) / (256 * 4), 256, 0, stream>>>(x, xb);
  cvt_wt_kernel<<<dim3(EMB / 32, EMB / 32, 4), dim3(32, 8), 0, stream>>>(
      Wq, Wk, Wv, Wo, Wqt, Wkt, Wvt, Wot);

  gemm_qkv<<<dim3(EMB / 128, MTOT / 128, 3), 256, 0, stream>>>(
      xb, Wqt, Wkt, Wvt, bq, bk, bv, Qb, Kb, Vtb);

  attn_fwd<<<dim3(16, NBATCH * HEADS), 512, 0, stream>>>(Qb, Kb, Vtb, Ob);

  gemm_out<<<dim3(EMB / 128, MTOT / 64), 256, 0, stream>>>(Ob, Wot, bo, (float*)d_out);
}

// Round 5
// 233.177 us; speedup vs baseline: 1.0614x; 1.0614x over previous
//
#include <hip/hip_runtime.h>

#define HEADS  16
#define DH     64
#define SEQ    2048
#define NBATCH 2
#define EMB    1024
#define MTOT   (NBATCH * SEQ)  // 4096

// Q pre-scale: 1/sqrt(1024) * log2(e)  (softmax done in base 2)
#define QSCALE 0.045084220027780106f

typedef short  s16x8 __attribute__((ext_vector_type(8)));
typedef float  f32x4 __attribute__((ext_vector_type(4)));
typedef unsigned short u16;
typedef unsigned short u16x4 __attribute__((ext_vector_type(4)));

__device__ __forceinline__ u16 f2bf(float f) {
  unsigned u = __builtin_bit_cast(unsigned, f);
  u += 0x7fffu + ((u >> 16) & 1u);   // RNE
  return (u16)(u >> 16);
}

// async global->LDS, 16B per lane; lds ptr wave-uniform base (HW adds lane*16)
__device__ __forceinline__ void gll16(const u16* g, u16* l) {
  __builtin_amdgcn_global_load_lds(
      (const __attribute__((address_space(1))) unsigned int*)g,
      (__attribute__((address_space(3))) unsigned int*)l, 16, 0, 0);
}

// ---------------- fp32 -> bf16 bulk convert (x) ----------------
__global__ void cvt_x_kernel(const float* __restrict__ x, u16* __restrict__ xb) {
  int i = (blockIdx.x * 256 + threadIdx.x) * 4;
  float4 v = *(const float4*)(x + i);
  u16x4 o;
  o.x = f2bf(v.x); o.y = f2bf(v.y); o.z = f2bf(v.z); o.w = f2bf(v.w);
  *(u16x4*)(xb + i) = o;
}

// ---------------- weight transpose + convert: Wt[n][k] = bf16(W[k][n]) ----------------
__global__ void cvt_wt_kernel(const float* __restrict__ Wq, const float* __restrict__ Wk,
                              const float* __restrict__ Wv, const float* __restrict__ Wo,
                              u16* __restrict__ Wqt, u16* __restrict__ Wkt,
                              u16* __restrict__ Wvt, u16* __restrict__ Wot) {
  __shared__ float tile[32][33];
  const float* W; u16* T;
  switch (blockIdx.z) {
    case 0:  W = Wq; T = Wqt; break;
    case 1:  W = Wk; T = Wkt; break;
    case 2:  W = Wv; T = Wvt; break;
    default: W = Wo; T = Wot; break;
  }
  int n0 = blockIdx.x * 32, k0 = blockIdx.y * 32;
  int tx = threadIdx.x, ty = threadIdx.y;
#pragma unroll
  for (int r = 0; r < 32; r += 8)
    tile[ty + r][tx] = W[(size_t)(k0 + ty + r) * EMB + n0 + tx];
  __syncthreads();
#pragma unroll
  for (int r = 0; r < 32; r += 8)
    T[(size_t)(n0 + ty + r) * EMB + k0 + tx] = f2bf(tile[tx][ty + r]);
}

// ---------------- GEMM mainloop: BM=128, BN=64, BK=64, 256 thr / 4 waves (2x2) ----------
__device__ __forceinline__ void gemm_core(const u16* __restrict__ A, const u16* __restrict__ Bt,
                                          u16* As, u16* Bs, int m0, int n0, f32x4 acc[4][2]) {
  const int tid = threadIdx.x;
  const int lane = tid & 63, w = tid >> 6;
  const int wm = w >> 1, wn = w & 1;
  const int lr = lane & 15, lq = lane >> 4;
#pragma unroll
  for (int i = 0; i < 4; i++)
#pragma unroll
    for (int j = 0; j < 2; j++)
      acc[i][j] = (f32x4){0.f, 0.f, 0.f, 0.f};

  for (int k0 = 0; k0 < EMB; k0 += 64) {
    __syncthreads();
#pragma unroll
    for (int j = 0; j < 4; j++) {
      int c = tid + 256 * j;
      gll16(&A[(size_t)(m0 + (c >> 3)) * EMB + k0 + (c & 7) * 8],
            &As[(w * 64 + 256 * j) * 8]);
    }
#pragma unroll
    for (int j = 0; j < 2; j++) {
      int c = tid + 256 * j;
      gll16(&Bt[(size_t)(n0 + (c >> 3)) * EMB + k0 + (c & 7) * 8],
            &Bs[(w * 64 + 256 * j) * 8]);
    }
    __syncthreads();
#pragma unroll
    for (int kk = 0; kk < 64; kk += 32) {
      s16x8 af[4], bf[2];
#pragma unroll
      for (int i = 0; i < 4; i++)
        af[i] = *(const s16x8*)&As[(wm * 64 + i * 16 + lr) * 64 + kk + lq * 8];
#pragma unroll
      for (int j = 0; j < 2; j++)
        bf[j] = *(const s16x8*)&Bs[(wn * 32 + j * 16 + lr) * 64 + kk + lq * 8];
#pragma unroll
      for (int i = 0; i < 4; i++)
#pragma unroll
        for (int j = 0; j < 2; j++)
          acc[i][j] = __builtin_amdgcn_mfma_f32_16x16x32_bf16(af[i], bf[j], acc[i][j], 0, 0, 0);
    }
  }
}

// QKV fused: blockIdx.z selects {Wq->Qb (scaled), Wk->Kb, Wv->Vtb (transposed)}
__global__ __launch_bounds__(256) void gemm_qkv(const u16* __restrict__ xb,
                                                const u16* __restrict__ Wqt, const u16* __restrict__ Wkt,
                                                const u16* __restrict__ Wvt,
                                                const float* __restrict__ bq, const float* __restrict__ bk,
                                                const float* __restrict__ bv,
                                                u16* __restrict__ Qb, u16* __restrict__ Kb,
                                                u16* __restrict__ Vtb) {
  __shared__ __align__(16) u16 As[128 * 64];
  __shared__ __align__(16) u16 Bs[64 * 64];
  const u16* Bt; const float* bias; u16* out; const int mode = blockIdx.z;
  switch (mode) {
    case 0:  Bt = Wqt; bias = bq; out = Qb;  break;
    case 1:  Bt = Wkt; bias = bk; out = Kb;  break;
    default: Bt = Wvt; bias = bv; out = Vtb; break;
  }
  const int m0 = blockIdx.y * 128, n0 = blockIdx.x * 64;
  f32x4 acc[4][2];
  gemm_core(xb, Bt, As, Bs, m0, n0, acc);

  const int tid = threadIdx.x, lane = tid & 63, w = tid >> 6;
  const int wm = w >> 1, wn = w & 1;
  const int lr = lane & 15, lq = lane >> 4;
#pragma unroll
  for (int i = 0; i < 4; i++) {
#pragma unroll
    for (int j = 0; j < 2; j++) {
      int col   = n0 + wn * 32 + j * 16 + lr;
      int mbase = m0 + wm * 64 + i * 16 + lq * 4;
      float bv_ = bias[col];
      int h = col >> 6, d = col & 63;
      if (mode == 0) {
#pragma unroll
        for (int r = 0; r < 4; r++) {
          int m = mbase + r, b = m >> 11, s = m & (SEQ - 1);
          out[((size_t)(b * HEADS + h) * SEQ + s) * DH + d] = f2bf((acc[i][j][r] + bv_) * QSCALE);
        }
      } else if (mode == 1) {
#pragma unroll
        for (int r = 0; r < 4; r++) {
          int m = mbase + r, b = m >> 11, s = m & (SEQ - 1);
          out[((size_t)(b * HEADS + h) * SEQ + s) * DH + d] = f2bf(acc[i][j][r] + bv_);
        }
      } else {
        int b = mbase >> 11, s = mbase & (SEQ - 1);
        u16x4 pk;
        pk.x = f2bf(acc[i][j][0] + bv_);
        pk.y = f2bf(acc[i][j][1] + bv_);
        pk.z = f2bf(acc[i][j][2] + bv_);
        pk.w = f2bf(acc[i][j][3] + bv_);
        *(u16x4*)&out[((size_t)(b * HEADS + h) * DH + d) * SEQ + s] = pk;
      }
    }
  }
}

// output projection: fp32 out, BM=128, BN=64
__global__ __launch_bounds__(256) void gemm_out(const u16* __restrict__ A, const u16* __restrict__ Bt,
                                                const float* __restrict__ bias, float* __restrict__ out) {
  __shared__ __align__(16) u16 As[128 * 64];
  __shared__ __align__(16) u16 Bs[64 * 64];
  const int m0 = blockIdx.y * 128, n0 = blockIdx.x * 64;
  f32x4 acc[4][2];
  gemm_core(A, Bt, As, Bs, m0, n0, acc);

  const int tid = threadIdx.x, lane = tid & 63, w = tid >> 6;
  const int wm = w >> 1, wn = w & 1;
  const int lr = lane & 15, lq = lane >> 4;
#pragma unroll
  for (int i = 0; i < 4; i++) {
#pragma unroll
    for (int j = 0; j < 2; j++) {
      int col   = n0 + wn * 32 + j * 16 + lr;
      int mbase = m0 + wm * 64 + i * 16 + lq * 4;
      float bv_ = bias[col];
#pragma unroll
      for (int r = 0; r < 4; r++)
        out[(size_t)(mbase + r) * EMB + col] = acc[i][j][r] + bv_;
    }
  }
}

// ---------------- fused causal attention: 1 q-tile (64 rows) per 256-thr block ----------
// grid (32, B*H), qt = 31-bx (long blocks first). Fixed-max base-2 softmax (Q pre-scaled),
// row-sum accumulated via ones-row MFMA (Vs d-rows 64..79).
__global__ __launch_bounds__(256) void attn_fwd(const u16* __restrict__ Q,
                                                const u16* __restrict__ Kg,
                                                const u16* __restrict__ Vt,
                                                u16* __restrict__ O) {
  __shared__ __align__(16) u16 Ks[64 * 72];      // [key][d], stride 72 (2-way free)
  __shared__ __align__(16) u16 Vs[80 * 72];      // [d][key]; rows 64..79 = sum rows
  __shared__ __align__(16) u16 Ps[4][16 * 72];   // per-wave P tile [qrow][key]
  const int tid = threadIdx.x, lane = tid & 63, w = tid >> 6;
  const int lr = lane & 15, lq = lane >> 4;
  const int bh = blockIdx.y;
  const int qt = 31 - blockIdx.x;
  const int rowoff = w * 16;
  const int qrow_g = qt * 64 + rowoff + lq * 4;   // + r
  const size_t qkbase = (size_t)bh * SEQ * DH;
  const size_t vbase  = (size_t)bh * DH * SEQ;
  const u16* kgp = Kg + qkbase;
  const u16* vtp = Vt + vbase;

  // ones/zeros init of Vs sum-rows 64..79 (never overwritten: staging touches rows < 64)
  {
    int r = tid >> 4, c = (tid & 15) * 4;
    u16 one = 0x3F80;
    u16x4 val = (r == 0) ? (u16x4){one, one, one, one} : (u16x4){0, 0, 0, 0};
    *(u16x4*)&Vs[(64 + r) * 72 + c] = val;
  }

  s16x8 qf0, qf1;
  {
    const u16* qrow = Q + qkbase + (size_t)(qt * 64 + rowoff + lr) * DH;
    qf0 = *(const s16x8*)&qrow[lq * 8];
    qf1 = *(const s16x8*)&qrow[32 + lq * 8];
  }
  f32x4 o[4], osum;
#pragma unroll
  for (int t = 0; t < 4; t++) o[t] = (f32x4){0.f, 0.f, 0.f, 0.f};
  osum = (f32x4){0.f, 0.f, 0.f, 0.f};

  // staging: 256 thr, 2x16B K-chunks + 2x16B V-chunks each (8 KB K + 8 KB V)
  const int srow = tid >> 3, soff = (tid & 7) * 8;        // chunk c=tid    -> row 0..31?  (c>>3: 0..31)
  const int srow2 = (tid + 256) >> 3;                     // chunk c=tid+256 -> row 32..63
  s16x8 kr0 = *(const s16x8*)&kgp[(size_t)srow * DH + soff];
  s16x8 kr1 = *(const s16x8*)&kgp[(size_t)srow2 * DH + soff];
  s16x8 vr0 = *(const s16x8*)&vtp[(size_t)srow * SEQ + soff];
  s16x8 vr1 = *(const s16x8*)&vtp[(size_t)srow2 * SEQ + soff];

  const int nkt = qt + 1;
  for (int kt = 0; kt < nkt; ++kt) {
    const int kb = kt * 64;
    __syncthreads();   // previous iteration's LDS readers done (also covers Vs init)
    *(s16x8*)&Ks[srow  * 72 + soff] = kr0;
    *(s16x8*)&Ks[srow2 * 72 + soff] = kr1;
    *(s16x8*)&Vs[srow  * 72 + soff] = vr0;
    *(s16x8*)&Vs[srow2 * 72 + soff] = vr1;
    __syncthreads();
    if (kt + 1 < nkt) {  // register prefetch of next tile (overlaps compute)
      int nb = kb + 64;
      kr0 = *(const s16x8*)&kgp[(size_t)(nb + srow) * DH + soff];
      kr1 = *(const s16x8*)&kgp[(size_t)(nb + srow2) * DH + soff];
      vr0 = *(const s16x8*)&vtp[(size_t)srow * SEQ + nb + soff];
      vr1 = *(const s16x8*)&vtp[(size_t)srow2 * SEQ + nb + soff];
    }

    // S = Q @ K^T (16 x 64 per wave); scores already in log2 domain
    f32x4 sc[4];
#pragma unroll
    for (int t = 0; t < 4; t++) {
      s16x8 kf0 = *(const s16x8*)&Ks[(t * 16 + lr) * 72 + lq * 8];
      s16x8 kf1 = *(const s16x8*)&Ks[(t * 16 + lr) * 72 + 32 + lq * 8];
      f32x4 z = (f32x4){0.f, 0.f, 0.f, 0.f};
      z = __builtin_amdgcn_mfma_f32_16x16x32_bf16(qf0, kf0, z, 0, 0, 0);
      z = __builtin_amdgcn_mfma_f32_16x16x32_bf16(qf1, kf1, z, 0, 0, 0);
      sc[t] = z;
    }

    // fixed-max softmax: p = exp2(s); masked keys -> 0
    const bool lastt = (kt == qt);
    if (lastt) {
#pragma unroll
      for (int t = 0; t < 4; t++)
#pragma unroll
        for (int r = 0; r < 4; r++)
          if ((t * 16 + lr) > (rowoff + lq * 4 + r)) sc[t][r] = -1e9f;
    }
#pragma unroll
    for (int t = 0; t < 4; t++)
#pragma unroll
      for (int r = 0; r < 4; r++)
        sc[t][r] = __builtin_amdgcn_exp2f(sc[t][r]);

    // P -> LDS (per-wave buffer, barrier-free)
    u16* pw = &Ps[w][0];
#pragma unroll
    for (int t = 0; t < 4; t++)
#pragma unroll
      for (int r = 0; r < 4; r++)
        pw[(lq * 4 + r) * 72 + t * 16 + lr] = f2bf(sc[t][r]);

    // O += P @ V  (+ sum block t=4 accumulating row-sums into osum via ones-row)
#pragma unroll
    for (int kc = 0; kc < 2; kc++) {
      s16x8 pf = *(const s16x8*)&pw[lr * 72 + kc * 32 + lq * 8];
#pragma unroll
      for (int t = 0; t < 4; t++) {
        s16x8 vf = *(const s16x8*)&Vs[(t * 16 + lr) * 72 + kc * 32 + lq * 8];
        o[t] = __builtin_amdgcn_mfma_f32_16x16x32_bf16(pf, vf, o[t], 0, 0, 0);
      }
      s16x8 sf = *(const s16x8*)&Vs[(64 + lr) * 72 + kc * 32 + lq * 8];
      osum = __builtin_amdgcn_mfma_f32_16x16x32_bf16(pf, sf, osum, 0, 0, 0);
    }
  }

  // lsum lives in lanes with lr==0 (col 64 of sum block); broadcast + rcp
  float inv[4];
#pragma unroll
  for (int r = 0; r < 4; r++)
    inv[r] = __builtin_amdgcn_rcpf(__shfl(osum[r], lq * 16));

  // epilogue: O[m][h*64+d] bf16
  const int b = bh >> 4, hh = bh & 15;
#pragma unroll
  for (int t = 0; t < 4; t++) {
#pragma unroll
    for (int r = 0; r < 4; r++) {
      int m = b * SEQ + qt * 64 + rowoff + lq * 4 + r;
      O[(size_t)m * EMB + hh * 64 + t * 16 + lr] = f2bf(o[t][r] * inv[r]);
    }
  }
}

extern "C" void kernel_launch(void* const* d_in, const int* in_sizes, int n_in,
                              void* d_out, int out_size, void* d_ws, size_t ws_size,
                              hipStream_t stream) {
  const float* x  = (const float*)d_in[0];
  const float* Wq = (const float*)d_in[2];
  const float* bq = (const float*)d_in[3];
  const float* Wk = (const float*)d_in[4];
  const float* bk = (const float*)d_in[5];
  const float* Wv = (const float*)d_in[6];
  const float* bv = (const float*)d_in[7];
  const float* Wo = (const float*)d_in[8];
  const float* bo = (const float*)d_in[9];

  char* ws = (char*)d_ws;
  const size_t MB = 1024 * 1024;
  u16* Qb  = (u16*)(ws + 0 * MB);    // [B][H][S][Dh] bf16 (pre-scaled by QSCALE)
  u16* Kb  = (u16*)(ws + 8 * MB);    // [B][H][S][Dh] bf16
  u16* Vtb = (u16*)(ws + 16 * MB);   // [B][H][Dh][S] bf16
  u16* xb  = (u16*)(ws + 24 * MB);   // [M][E] bf16
  u16* Ob  = xb;                     // alias: xb dead after QKV GEMMs
  u16* Wqt = (u16*)(ws + 32 * MB);
  u16* Wkt = (u16*)(ws + 34 * MB);
  u16* Wvt = (u16*)(ws + 36 * MB);
  u16* Wot = (u16*)(ws + 38 * MB);

  cvt_x_kernel<<<(MTOT * EMB) / (256 * 4), 256, 0, stream>>>(x, xb);
  cvt_wt_kernel<<<dim3(EMB / 32, EMB / 32, 4), dim3(32, 8), 0, stream>>>(
      Wq, Wk, Wv, Wo, Wqt, Wkt, Wvt, Wot);

  gemm_qkv<<<dim3(EMB / 64, MTOT / 128, 3), 256, 0, stream>>>(
      xb, Wqt, Wkt, Wvt, bq, bk, bv, Qb, Kb, Vtb);

  attn_fwd<<<dim3(32, NBATCH * HEADS), 256, 0, stream>>>(Qb, Kb, Vtb, Ob);

  gemm_out<<<dim3(EMB / 64, MTOT / 128), 256, 0, stream>>>(Ob, Wot, bo, (float*)d_out);
}

// Round 6
// 201.973 us; speedup vs baseline: 1.2254x; 1.1545x over previous
//
#include <hip/hip_runtime.h>

#define HEADS  16
#define DH     64
#define SEQ    2048
#define NBATCH 2
#define EMB    1024
#define MTOT   (NBATCH * SEQ)  // 4096

// Q pre-scale: 1/sqrt(1024) * log2(e)  (softmax done in base 2, fixed-max)
#define QSCALE 0.045084220027780106f

typedef short  s16x8 __attribute__((ext_vector_type(8)));
typedef float  f32x4 __attribute__((ext_vector_type(4)));
typedef unsigned short u16;
typedef unsigned short u16x4 __attribute__((ext_vector_type(4)));

__device__ __forceinline__ u16 f2bf(float f) {
  unsigned u = __builtin_bit_cast(unsigned, f);
  u += 0x7fffu + ((u >> 16) & 1u);   // RNE
  return (u16)(u >> 16);
}

// async global->LDS, 16B per lane; lds ptr wave-uniform base (HW adds lane*16)
__device__ __forceinline__ void gll16(const u16* g, u16* l) {
  __builtin_amdgcn_global_load_lds(
      (const __attribute__((address_space(1))) unsigned int*)g,
      (__attribute__((address_space(3))) unsigned int*)l, 16, 0, 0);
}

// ---------------- fp32 -> bf16 bulk convert (x) ----------------
__global__ void cvt_x_kernel(const float* __restrict__ x, u16* __restrict__ xb) {
  int i = (blockIdx.x * 256 + threadIdx.x) * 4;
  float4 v = *(const float4*)(x + i);
  u16x4 o;
  o.x = f2bf(v.x); o.y = f2bf(v.y); o.z = f2bf(v.z); o.w = f2bf(v.w);
  *(u16x4*)(xb + i) = o;
}

// ---------------- weight transpose + convert: Wt[n][k] = bf16(W[k][n]) ----------------
__global__ void cvt_wt_kernel(const float* __restrict__ Wq, const float* __restrict__ Wk,
                              const float* __restrict__ Wv, const float* __restrict__ Wo,
                              u16* __restrict__ Wqt, u16* __restrict__ Wkt,
                              u16* __restrict__ Wvt, u16* __restrict__ Wot) {
  __shared__ float tile[32][33];
  const float* W; u16* T;
  switch (blockIdx.z) {
    case 0:  W = Wq; T = Wqt; break;
    case 1:  W = Wk; T = Wkt; break;
    case 2:  W = Wv; T = Wvt; break;
    default: W = Wo; T = Wot; break;
  }
  int n0 = blockIdx.x * 32, k0 = blockIdx.y * 32;
  int tx = threadIdx.x, ty = threadIdx.y;
#pragma unroll
  for (int r = 0; r < 32; r += 8)
    tile[ty + r][tx] = W[(size_t)(k0 + ty + r) * EMB + n0 + tx];
  __syncthreads();
#pragma unroll
  for (int r = 0; r < 32; r += 8)
    T[(size_t)(n0 + ty + r) * EMB + k0 + tx] = f2bf(tile[tx][ty + r]);
}

// ---------------- GEMM mainloop: BM=128, BN=64, BK=64, 256 thr / 4 waves (2x2) ----------
__device__ __forceinline__ void gemm_core(const u16* __restrict__ A, const u16* __restrict__ Bt,
                                          u16* As, u16* Bs, int m0, int n0, f32x4 acc[4][2]) {
  const int tid = threadIdx.x;
  const int lane = tid & 63, w = tid >> 6;
  const int wm = w >> 1, wn = w & 1;
  const int lr = lane & 15, lq = lane >> 4;
#pragma unroll
  for (int i = 0; i < 4; i++)
#pragma unroll
    for (int j = 0; j < 2; j++)
      acc[i][j] = (f32x4){0.f, 0.f, 0.f, 0.f};

  for (int k0 = 0; k0 < EMB; k0 += 64) {
    __syncthreads();
#pragma unroll
    for (int j = 0; j < 4; j++) {
      int c = tid + 256 * j;
      gll16(&A[(size_t)(m0 + (c >> 3)) * EMB + k0 + (c & 7) * 8],
            &As[(w * 64 + 256 * j) * 8]);
    }
#pragma unroll
    for (int j = 0; j < 2; j++) {
      int c = tid + 256 * j;
      gll16(&Bt[(size_t)(n0 + (c >> 3)) * EMB + k0 + (c & 7) * 8],
            &Bs[(w * 64 + 256 * j) * 8]);
    }
    __syncthreads();
#pragma unroll
    for (int kk = 0; kk < 64; kk += 32) {
      s16x8 af[4], bf[2];
#pragma unroll
      for (int i = 0; i < 4; i++)
        af[i] = *(const s16x8*)&As[(wm * 64 + i * 16 + lr) * 64 + kk + lq * 8];
#pragma unroll
      for (int j = 0; j < 2; j++)
        bf[j] = *(const s16x8*)&Bs[(wn * 32 + j * 16 + lr) * 64 + kk + lq * 8];
#pragma unroll
      for (int i = 0; i < 4; i++)
#pragma unroll
        for (int j = 0; j < 2; j++)
          acc[i][j] = __builtin_amdgcn_mfma_f32_16x16x32_bf16(af[i], bf[j], acc[i][j], 0, 0, 0);
    }
  }
}

// QKV fused: blockIdx.z selects {Wq->Qb (scaled), Wk->Kb, Wv->Vtb (transposed)}
__global__ __launch_bounds__(256) void gemm_qkv(const u16* __restrict__ xb,
                                                const u16* __restrict__ Wqt, const u16* __restrict__ Wkt,
                                                const u16* __restrict__ Wvt,
                                                const float* __restrict__ bq, const float* __restrict__ bk,
                                                const float* __restrict__ bv,
                                                u16* __restrict__ Qb, u16* __restrict__ Kb,
                                                u16* __restrict__ Vtb) {
  __shared__ __align__(16) u16 As[128 * 64];
  __shared__ __align__(16) u16 Bs[64 * 64];
  const u16* Bt; const float* bias; u16* out; const int mode = blockIdx.z;
  switch (mode) {
    case 0:  Bt = Wqt; bias = bq; out = Qb;  break;
    case 1:  Bt = Wkt; bias = bk; out = Kb;  break;
    default: Bt = Wvt; bias = bv; out = Vtb; break;
  }
  const int m0 = blockIdx.y * 128, n0 = blockIdx.x * 64;
  f32x4 acc[4][2];
  gemm_core(xb, Bt, As, Bs, m0, n0, acc);

  const int tid = threadIdx.x, lane = tid & 63, w = tid >> 6;
  const int wm = w >> 1, wn = w & 1;
  const int lr = lane & 15, lq = lane >> 4;
#pragma unroll
  for (int i = 0; i < 4; i++) {
#pragma unroll
    for (int j = 0; j < 2; j++) {
      int col   = n0 + wn * 32 + j * 16 + lr;
      int mbase = m0 + wm * 64 + i * 16 + lq * 4;
      float bv_ = bias[col];
      int h = col >> 6, d = col & 63;
      if (mode == 0) {
#pragma unroll
        for (int r = 0; r < 4; r++) {
          int m = mbase + r, b = m >> 11, s = m & (SEQ - 1);
          out[((size_t)(b * HEADS + h) * SEQ + s) * DH + d] = f2bf((acc[i][j][r] + bv_) * QSCALE);
        }
      } else if (mode == 1) {
#pragma unroll
        for (int r = 0; r < 4; r++) {
          int m = mbase + r, b = m >> 11, s = m & (SEQ - 1);
          out[((size_t)(b * HEADS + h) * SEQ + s) * DH + d] = f2bf(acc[i][j][r] + bv_);
        }
      } else {
        int b = mbase >> 11, s = mbase & (SEQ - 1);
        u16x4 pk;
        pk.x = f2bf(acc[i][j][0] + bv_);
        pk.y = f2bf(acc[i][j][1] + bv_);
        pk.z = f2bf(acc[i][j][2] + bv_);
        pk.w = f2bf(acc[i][j][3] + bv_);
        *(u16x4*)&out[((size_t)(b * HEADS + h) * DH + d) * SEQ + s] = pk;
      }
    }
  }
}

// output projection: fp32 out, BM=128, BN=64
__global__ __launch_bounds__(256) void gemm_out(const u16* __restrict__ A, const u16* __restrict__ Bt,
                                                const float* __restrict__ bias, float* __restrict__ out) {
  __shared__ __align__(16) u16 As[128 * 64];
  __shared__ __align__(16) u16 Bs[64 * 64];
  const int m0 = blockIdx.y * 128, n0 = blockIdx.x * 64;
  f32x4 acc[4][2];
  gemm_core(A, Bt, As, Bs, m0, n0, acc);

  const int tid = threadIdx.x, lane = tid & 63, w = tid >> 6;
  const int wm = w >> 1, wn = w & 1;
  const int lr = lane & 15, lq = lane >> 4;
#pragma unroll
  for (int i = 0; i < 4; i++) {
#pragma unroll
    for (int j = 0; j < 2; j++) {
      int col   = n0 + wn * 32 + j * 16 + lr;
      int mbase = m0 + wm * 64 + i * 16 + lq * 4;
      float bv_ = bias[col];
#pragma unroll
      for (int r = 0; r < 4; r++)
        out[(size_t)(mbase + r) * EMB + col] = acc[i][j][r] + bv_;
    }
  }
}

// ---------------- fused causal attention: paired q-tiles, uniform 17-iter blocks -------
// grid (16, B*H); 512 thr = 2 groups x 4 waves. Fixed-max base-2 softmax => output is a
// PURE SUM over k-tiles, so key ranges split across groups and combine by addition.
// Work list for pair (qtA=bx, qtB=31-bx): 33 jobs; group 0 = jobs 0..16 (all of tile A +
// prefix of tile B), group 1 = jobs 17..32 (suffix of tile B; one pad iteration).
// Group 0 writes tile A at its phase transition and reuses accumulators for tile B.
__global__ __launch_bounds__(512, 4) void attn_fwd(const u16* __restrict__ Q,
                                                   const u16* __restrict__ Kg,
                                                   const u16* __restrict__ Vt,
                                                   u16* __restrict__ O) {
  // carve (u16 units): KsA[64*80]=0, VsA[80*80]=5120, KsB=11520, VsB=16640, Ps=23040 (8x16x80)
  __shared__ __align__(16) u16 smem[33280];
  const int tid = threadIdx.x, lane = tid & 63, w = tid >> 6;
  const int g = w >> 2, wg = w & 3;
  const int lr = lane & 15, lq = lane >> 4;
  const int bh = blockIdx.y, bx = blockIdx.x;
  const int qtA = bx, qtB = 31 - bx;
  const int rowoff = wg * 16;
  u16* Ks = smem + (g ? 11520 : 0);
  u16* Vs = smem + (g ? 16640 : 5120);
  u16* pw = smem + 23040 + w * 1280;
  const size_t qkbase = (size_t)bh * SEQ * DH;
  const size_t vbase  = (size_t)bh * DH * SEQ;
  const u16* kgp = Kg + qkbase;
  const u16* vtp = Vt + vbase;
  const int t256 = tid & 255;
  const int b = bh >> 4, hh = bh & 15;

  // ones/zeros init of Vs sum-rows 64..79 (per group; staging only touches rows < 64)
  {
    int r = t256 >> 4, c = (t256 & 15) * 4;
    u16 one = 0x3F80;
    u16x4 val = (r == 0) ? (u16x4){one, one, one, one} : (u16x4){0, 0, 0, 0};
    *(u16x4*)&Vs[(64 + r) * 80 + c] = val;
  }

  // Q frags: group 0 starts on tile A, group 1 on tile B
  s16x8 qf0, qf1;
  {
    const int myqt0 = g ? qtB : qtA;
    const u16* qp = Q + qkbase + (size_t)(myqt0 * 64 + rowoff + lr) * DH;
    qf0 = *(const s16x8*)&qp[lq * 8];
    qf1 = *(const s16x8*)&qp[32 + lq * 8];
  }
  f32x4 o[4], os;
#pragma unroll
  for (int t = 0; t < 4; t++) o[t] = (f32x4){0.f, 0.f, 0.f, 0.f};
  os = (f32x4){0.f, 0.f, 0.f, 0.f};

  // staging: 256 thr/group, 2x16B K-chunks + 2x16B V-chunks each
  const int srow = t256 >> 3, soff = (t256 & 7) * 8;   // srow 0..31 (+32 second chunk)
  {
    int kt0 = g ? (16 - bx) : 0;
    // preload first tile into regs (written to LDS at i=0)
    // (group 1's kt0 = 16-bx is always <= qtB, valid)
    s16x8 tmp;
    (void)tmp;
  }
  int kt0 = g ? (16 - bx) : 0;
  s16x8 kr0 = *(const s16x8*)&kgp[(size_t)(kt0 * 64 + srow) * DH + soff];
  s16x8 kr1 = *(const s16x8*)&kgp[(size_t)(kt0 * 64 + srow + 32) * DH + soff];
  s16x8 vr0 = *(const s16x8*)&vtp[(size_t)srow * SEQ + kt0 * 64 + soff];
  s16x8 vr1 = *(const s16x8*)&vtp[(size_t)(srow + 32) * SEQ + kt0 * 64 + soff];

  for (int i = 0; i < 17; ++i) {
    __syncthreads();   // previous iteration's LDS readers done (covers init at i=0)
    *(s16x8*)&Ks[srow * 80 + soff]        = kr0;
    *(s16x8*)&Ks[(srow + 32) * 80 + soff] = kr1;
    *(s16x8*)&Vs[srow * 80 + soff]        = vr0;
    *(s16x8*)&Vs[(srow + 32) * 80 + soff] = vr1;
    __syncthreads();

    // register prefetch of next tile (overlaps compute)
    {
      bool hn = g ? (i + 1 < 16) : (i + 1 < 17);
      if (hn) {
        int ktn = g ? (17 + i - bx) : ((i + 1 <= qtA) ? (i + 1) : (i - qtA));
        kr0 = *(const s16x8*)&kgp[(size_t)(ktn * 64 + srow) * DH + soff];
        kr1 = *(const s16x8*)&kgp[(size_t)(ktn * 64 + srow + 32) * DH + soff];
        vr0 = *(const s16x8*)&vtp[(size_t)srow * SEQ + ktn * 64 + soff];
        vr1 = *(const s16x8*)&vtp[(size_t)(srow + 32) * SEQ + ktn * 64 + soff];
      }
    }

    // group-0 phase transition: tile A complete -> write it, reset acc, switch Q to tile B
    if (g == 0 && i == qtA + 1) {
      float inv[4];
#pragma unroll
      for (int r = 0; r < 4; r++) inv[r] = __builtin_amdgcn_rcpf(__shfl(os[r], lq * 16));
#pragma unroll
      for (int t = 0; t < 4; t++)
#pragma unroll
        for (int r = 0; r < 4; r++) {
          int m = b * SEQ + qtA * 64 + rowoff + lq * 4 + r;
          O[(size_t)m * EMB + hh * 64 + t * 16 + lr] = f2bf(o[t][r] * inv[r]);
        }
#pragma unroll
      for (int t = 0; t < 4; t++) o[t] = (f32x4){0.f, 0.f, 0.f, 0.f};
      os = (f32x4){0.f, 0.f, 0.f, 0.f};
      const u16* qp = Q + qkbase + (size_t)(qtB * 64 + rowoff + lr) * DH;
      qf0 = *(const s16x8*)&qp[lq * 8];
      qf1 = *(const s16x8*)&qp[32 + lq * 8];
    }

    const bool docomp = g ? (i < 16) : true;
    if (docomp) {
      // S = Q @ K^T (16 x 64 per wave); scores in log2 domain (Q pre-scaled)
      f32x4 sc[4];
#pragma unroll
      for (int t = 0; t < 4; t++) {
        s16x8 kf0 = *(const s16x8*)&Ks[(t * 16 + lr) * 80 + lq * 8];
        s16x8 kf1 = *(const s16x8*)&Ks[(t * 16 + lr) * 80 + 32 + lq * 8];
        f32x4 z = (f32x4){0.f, 0.f, 0.f, 0.f};
        z = __builtin_amdgcn_mfma_f32_16x16x32_bf16(qf0, kf0, z, 0, 0, 0);
        z = __builtin_amdgcn_mfma_f32_16x16x32_bf16(qf1, kf1, z, 0, 0, 0);
        sc[t] = z;
      }
      // diagonal mask: group0 hits tile-A diag at i==qtA; group1 hits tile-B diag at i==15
      const bool diag = g ? (i == 15) : (i == qtA);
      if (diag) {
#pragma unroll
        for (int t = 0; t < 4; t++)
#pragma unroll
          for (int r = 0; r < 4; r++)
            if ((t * 16 + lr) > (rowoff + lq * 4 + r)) sc[t][r] = -1e9f;
      }
#pragma unroll
      for (int t = 0; t < 4; t++)
#pragma unroll
        for (int r = 0; r < 4; r++)
          sc[t][r] = __builtin_amdgcn_exp2f(sc[t][r]);

      // P -> per-wave LDS (barrier-free), back as A-operand
#pragma unroll
      for (int t = 0; t < 4; t++)
#pragma unroll
        for (int r = 0; r < 4; r++)
          pw[(lq * 4 + r) * 80 + t * 16 + lr] = f2bf(sc[t][r]);

      // O += P @ V  (+ row-sum via ones-row block)
#pragma unroll
      for (int kc = 0; kc < 2; kc++) {
        s16x8 pf = *(const s16x8*)&pw[lr * 80 + kc * 32 + lq * 8];
#pragma unroll
        for (int t = 0; t < 4; t++) {
          s16x8 vf = *(const s16x8*)&Vs[(t * 16 + lr) * 80 + kc * 32 + lq * 8];
          o[t] = __builtin_amdgcn_mfma_f32_16x16x32_bf16(pf, vf, o[t], 0, 0, 0);
        }
        s16x8 sf = *(const s16x8*)&Vs[(64 + lr) * 80 + kc * 32 + lq * 8];
        os = __builtin_amdgcn_mfma_f32_16x16x32_bf16(pf, sf, os, 0, 0, 0);
      }
    }
  }

  // ---- combine tile B: group 0's partial (fp32) added into group 1's, then write ----
  __syncthreads();
  float* Cb = (float*)smem;             // [64][68] fp32 partials (over group-0 K/V bufs)
  float* Ss = (float*)(smem + 23040);   // 64 partial row-sums (over Ps region)
  if (g == 0) {
#pragma unroll
    for (int t = 0; t < 4; t++)
#pragma unroll
      for (int r = 0; r < 4; r++)
        Cb[(rowoff + lq * 4 + r) * 68 + t * 16 + lr] = o[t][r];
#pragma unroll
    for (int r = 0; r < 4; r++) {
      float s = __shfl(os[r], lq * 16);
      if (lr == 0) Ss[rowoff + lq * 4 + r] = s;
    }
  }
  __syncthreads();
  if (g == 1) {
    float inv[4];
#pragma unroll
    for (int r = 0; r < 4; r++)
      inv[r] = __builtin_amdgcn_rcpf(__shfl(os[r], lq * 16) + Ss[rowoff + lq * 4 + r]);
#pragma unroll
    for (int t = 0; t < 4; t++)
#pragma unroll
      for (int r = 0; r < 4; r++) {
        int m = b * SEQ + qtB * 64 + rowoff + lq * 4 + r;
        float v = o[t][r] + Cb[(rowoff + lq * 4 + r) * 68 + t * 16 + lr];
        O[(size_t)m * EMB + hh * 64 + t * 16 + lr] = f2bf(v * inv[r]);
      }
  }
}

extern "C" void kernel_launch(void* const* d_in, const int* in_sizes, int n_in,
                              void* d_out, int out_size, void* d_ws, size_t ws_size,
                              hipStream_t stream) {
  const float* x  = (const float*)d_in[0];
  const float* Wq = (const float*)d_in[2];
  const float* bq = (const float*)d_in[3];
  const float* Wk = (const float*)d_in[4];
  const float* bk = (const float*)d_in[5];
  const float* Wv = (const float*)d_in[6];
  const float* bv = (const float*)d_in[7];
  const float* Wo = (const float*)d_in[8];
  const float* bo = (const float*)d_in[9];

  char* ws = (char*)d_ws;
  const size_t MB = 1024 * 1024;
  u16* Qb  = (u16*)(ws + 0 * MB);    // [B][H][S][Dh] bf16 (pre-scaled by QSCALE)
  u16* Kb  = (u16*)(ws + 8 * MB);    // [B][H][S][Dh] bf16
  u16* Vtb = (u16*)(ws + 16 * MB);   // [B][H][Dh][S] bf16
  u16* xb  = (u16*)(ws + 24 * MB);   // [M][E] bf16
  u16* Ob  = xb;                     // alias: xb dead after QKV GEMMs
  u16* Wqt = (u16*)(ws + 32 * MB);
  u16* Wkt = (u16*)(ws + 34 * MB);
  u16* Wvt = (u16*)(ws + 36 * MB);
  u16* Wot = (u16*)(ws + 38 * MB);

  cvt_x_kernel<<<(MTOT * EMB) / (256 * 4), 256, 0, stream>>>(x, xb);
  cvt_wt_kernel<<<dim3(EMB / 32, EMB / 32, 4), dim3(32, 8), 0, stream>>>(
      Wq, Wk, Wv, Wo, Wqt, Wkt, Wvt, Wot);

  gemm_qkv<<<dim3(EMB / 64, MTOT / 128, 3), 256, 0, stream>>>(
      xb, Wqt, Wkt, Wvt, bq, bk, bv, Qb, Kb, Vtb);

  attn_fwd<<<dim3(16, NBATCH * HEADS), 512, 0, stream>>>(Qb, Kb, Vtb, Ob);

  gemm_out<<<dim3(EMB / 64, MTOT / 128), 256, 0, stream>>>(Ob, Wot, bo, (float*)d_out);
}

// Round 7
// 187.828 us; speedup vs baseline: 1.3176x; 1.0753x over previous
//
#include <hip/hip_runtime.h>

#define HEADS  16
#define DH     64
#define SEQ    2048
#define NBATCH 2
#define EMB    1024
#define MTOT   (NBATCH * SEQ)  // 4096

// Q pre-scale: 1/sqrt(1024) * log2(e)  (softmax done in base 2, fixed-max)
#define QSCALE 0.045084220027780106f

typedef short  s16x8 __attribute__((ext_vector_type(8)));
typedef float  f32x4 __attribute__((ext_vector_type(4)));
typedef unsigned short u16;
typedef unsigned short u16x4 __attribute__((ext_vector_type(4)));

__device__ __forceinline__ u16 f2bf(float f) {
  unsigned u = __builtin_bit_cast(unsigned, f);
  u += 0x7fffu + ((u >> 16) & 1u);   // RNE
  return (u16)(u >> 16);
}

// async global->LDS, 16B per lane; lds ptr wave-uniform base (HW adds lane*16)
__device__ __forceinline__ void gll16(const u16* g, u16* l) {
  __builtin_amdgcn_global_load_lds(
      (const __attribute__((address_space(1))) unsigned int*)g,
      (__attribute__((address_space(3))) unsigned int*)l, 16, 0, 0);
}

// ---------------- fp32 -> bf16 bulk convert (x) ----------------
__global__ void cvt_x_kernel(const float* __restrict__ x, u16* __restrict__ xb) {
  int i = (blockIdx.x * 256 + threadIdx.x) * 4;
  float4 v = *(const float4*)(x + i);
  u16x4 o;
  o.x = f2bf(v.x); o.y = f2bf(v.y); o.z = f2bf(v.z); o.w = f2bf(v.w);
  *(u16x4*)(xb + i) = o;
}

// ---------------- weight transpose + convert: Wt[n][k] = bf16(W[k][n]) ----------------
__global__ void cvt_wt_kernel(const float* __restrict__ Wq, const float* __restrict__ Wk,
                              const float* __restrict__ Wv, const float* __restrict__ Wo,
                              u16* __restrict__ Wqt, u16* __restrict__ Wkt,
                              u16* __restrict__ Wvt, u16* __restrict__ Wot) {
  __shared__ float tile[32][33];
  const float* W; u16* T;
  switch (blockIdx.z) {
    case 0:  W = Wq; T = Wqt; break;
    case 1:  W = Wk; T = Wkt; break;
    case 2:  W = Wv; T = Wvt; break;
    default: W = Wo; T = Wot; break;
  }
  int n0 = blockIdx.x * 32, k0 = blockIdx.y * 32;
  int tx = threadIdx.x, ty = threadIdx.y;
#pragma unroll
  for (int r = 0; r < 32; r += 8)
    tile[ty + r][tx] = W[(size_t)(k0 + ty + r) * EMB + n0 + tx];
  __syncthreads();
#pragma unroll
  for (int r = 0; r < 32; r += 8)
    T[(size_t)(n0 + ty + r) * EMB + k0 + tx] = f2bf(tile[tx][ty + r]);
}

// ---------------- GEMM mainloop: BM=128, BN=64, BK=64, 256 thr / 4 waves (2x2) ----------
// LDS layout XOR-swizzled: physical 16B-chunk p of row holds logical chunk (p&7)^(row&7).
// Staging permutes each lane's GLOBAL chunk (same 128B window -> still coalesced);
// fragment reads XOR the chunk index by (row&7) -> all 32 banks covered, 2-way only.
__device__ __forceinline__ void gemm_core(const u16* __restrict__ A, const u16* __restrict__ Bt,
                                          u16* As, u16* Bs, int m0, int n0, f32x4 acc[4][2]) {
  const int tid = threadIdx.x;
  const int lane = tid & 63, w = tid >> 6;
  const int wm = w >> 1, wn = w & 1;
  const int lr = lane & 15, lq = lane >> 4;
#pragma unroll
  for (int i = 0; i < 4; i++)
#pragma unroll
    for (int j = 0; j < 2; j++)
      acc[i][j] = (f32x4){0.f, 0.f, 0.f, 0.f};

  for (int k0 = 0; k0 < EMB; k0 += 64) {
    __syncthreads();
#pragma unroll
    for (int j = 0; j < 4; j++) {
      int c = tid + 256 * j;
      int row = c >> 3, c8 = (c & 7) ^ (row & 7);
      gll16(&A[(size_t)(m0 + row) * EMB + k0 + c8 * 8],
            &As[(w * 64 + 256 * j) * 8]);
    }
#pragma unroll
    for (int j = 0; j < 2; j++) {
      int c = tid + 256 * j;
      int row = c >> 3, c8 = (c & 7) ^ (row & 7);
      gll16(&Bt[(size_t)(n0 + row) * EMB + k0 + c8 * 8],
            &Bs[(w * 64 + 256 * j) * 8]);
    }
    __syncthreads();
#pragma unroll
    for (int kk8 = 0; kk8 < 8; kk8 += 4) {
      s16x8 af[4], bf[2];
#pragma unroll
      for (int i = 0; i < 4; i++) {
        int row = wm * 64 + i * 16 + lr;
        af[i] = *(const s16x8*)&As[row * 64 + (((kk8 + lq) ^ (row & 7)) * 8)];
      }
#pragma unroll
      for (int j = 0; j < 2; j++) {
        int row = wn * 32 + j * 16 + lr;
        bf[j] = *(const s16x8*)&Bs[row * 64 + (((kk8 + lq) ^ (row & 7)) * 8)];
      }
#pragma unroll
      for (int i = 0; i < 4; i++)
#pragma unroll
        for (int j = 0; j < 2; j++)
          acc[i][j] = __builtin_amdgcn_mfma_f32_16x16x32_bf16(af[i], bf[j], acc[i][j], 0, 0, 0);
    }
  }
}

// QKV fused: blockIdx.z selects {Wq->Qb (scaled), Wk->Kb, Wv->Vtb (transposed)}
__global__ __launch_bounds__(256) void gemm_qkv(const u16* __restrict__ xb,
                                                const u16* __restrict__ Wqt, const u16* __restrict__ Wkt,
                                                const u16* __restrict__ Wvt,
                                                const float* __restrict__ bq, const float* __restrict__ bk,
                                                const float* __restrict__ bv,
                                                u16* __restrict__ Qb, u16* __restrict__ Kb,
                                                u16* __restrict__ Vtb) {
  __shared__ __align__(16) u16 As[128 * 64];
  __shared__ __align__(16) u16 Bs[64 * 64];
  const u16* Bt; const float* bias; u16* out; const int mode = blockIdx.z;
  switch (mode) {
    case 0:  Bt = Wqt; bias = bq; out = Qb;  break;
    case 1:  Bt = Wkt; bias = bk; out = Kb;  break;
    default: Bt = Wvt; bias = bv; out = Vtb; break;
  }
  const int m0 = blockIdx.y * 128, n0 = blockIdx.x * 64;
  f32x4 acc[4][2];
  gemm_core(xb, Bt, As, Bs, m0, n0, acc);

  const int tid = threadIdx.x, lane = tid & 63, w = tid >> 6;
  const int wm = w >> 1, wn = w & 1;
  const int lr = lane & 15, lq = lane >> 4;
#pragma unroll
  for (int i = 0; i < 4; i++) {
#pragma unroll
    for (int j = 0; j < 2; j++) {
      int col   = n0 + wn * 32 + j * 16 + lr;
      int mbase = m0 + wm * 64 + i * 16 + lq * 4;
      float bv_ = bias[col];
      int h = col >> 6, d = col & 63;
      if (mode == 0) {
#pragma unroll
        for (int r = 0; r < 4; r++) {
          int m = mbase + r, b = m >> 11, s = m & (SEQ - 1);
          out[((size_t)(b * HEADS + h) * SEQ + s) * DH + d] = f2bf((acc[i][j][r] + bv_) * QSCALE);
        }
      } else if (mode == 1) {
#pragma unroll
        for (int r = 0; r < 4; r++) {
          int m = mbase + r, b = m >> 11, s = m & (SEQ - 1);
          out[((size_t)(b * HEADS + h) * SEQ + s) * DH + d] = f2bf(acc[i][j][r] + bv_);
        }
      } else {
        int b = mbase >> 11, s = mbase & (SEQ - 1);
        u16x4 pk;
        pk.x = f2bf(acc[i][j][0] + bv_);
        pk.y = f2bf(acc[i][j][1] + bv_);
        pk.z = f2bf(acc[i][j][2] + bv_);
        pk.w = f2bf(acc[i][j][3] + bv_);
        *(u16x4*)&out[((size_t)(b * HEADS + h) * DH + d) * SEQ + s] = pk;
      }
    }
  }
}

// output projection: fp32 out, BM=128, BN=64
__global__ __launch_bounds__(256) void gemm_out(const u16* __restrict__ A, const u16* __restrict__ Bt,
                                                const float* __restrict__ bias, float* __restrict__ out) {
  __shared__ __align__(16) u16 As[128 * 64];
  __shared__ __align__(16) u16 Bs[64 * 64];
  const int m0 = blockIdx.y * 128, n0 = blockIdx.x * 64;
  f32x4 acc[4][2];
  gemm_core(A, Bt, As, Bs, m0, n0, acc);

  const int tid = threadIdx.x, lane = tid & 63, w = tid >> 6;
  const int wm = w >> 1, wn = w & 1;
  const int lr = lane & 15, lq = lane >> 4;
#pragma unroll
  for (int i = 0; i < 4; i++) {
#pragma unroll
    for (int j = 0; j < 2; j++) {
      int col   = n0 + wn * 32 + j * 16 + lr;
      int mbase = m0 + wm * 64 + i * 16 + lq * 4;
      float bv_ = bias[col];
#pragma unroll
      for (int r = 0; r < 4; r++)
        out[(size_t)(mbase + r) * EMB + col] = acc[i][j][r] + bv_;
    }
  }
}

// ---------------- fused causal attention: paired q-tiles, uniform 17-iter blocks -------
// grid (16, B*H); 512 thr = 2 groups x 4 waves. Fixed-max base-2 softmax => output is a
// PURE SUM over k-tiles, so key ranges split across groups and combine by addition.
// Work list for pair (qtA=bx, qtB=31-bx): 33 jobs; group 0 = jobs 0..16 (all of tile A +
// prefix of tile B), group 1 = jobs 17..32 (suffix of tile B; one pad iteration).
// Group 0 writes tile A at its phase transition and reuses accumulators for tile B.
__global__ __launch_bounds__(512, 4) void attn_fwd(const u16* __restrict__ Q,
                                                   const u16* __restrict__ Kg,
                                                   const u16* __restrict__ Vt,
                                                   u16* __restrict__ O) {
  // carve (u16 units): KsA[64*80]=0, VsA[80*80]=5120, KsB=11520, VsB=16640, Ps=23040 (8x16x80)
  __shared__ __align__(16) u16 smem[33280];
  const int tid = threadIdx.x, lane = tid & 63, w = tid >> 6;
  const int g = w >> 2, wg = w & 3;
  const int lr = lane & 15, lq = lane >> 4;
  const int bh = blockIdx.y, bx = blockIdx.x;
  const int qtA = bx, qtB = 31 - bx;
  const int rowoff = wg * 16;
  u16* Ks = smem + (g ? 11520 : 0);
  u16* Vs = smem + (g ? 16640 : 5120);
  u16* pw = smem + 23040 + w * 1280;
  const size_t qkbase = (size_t)bh * SEQ * DH;
  const size_t vbase  = (size_t)bh * DH * SEQ;
  const u16* kgp = Kg + qkbase;
  const u16* vtp = Vt + vbase;
  const int t256 = tid & 255;
  const int b = bh >> 4, hh = bh & 15;

  // ones/zeros init of Vs sum-rows 64..79 (per group; staging only touches rows < 64)
  {
    int r = t256 >> 4, c = (t256 & 15) * 4;
    u16 one = 0x3F80;
    u16x4 val = (r == 0) ? (u16x4){one, one, one, one} : (u16x4){0, 0, 0, 0};
    *(u16x4*)&Vs[(64 + r) * 80 + c] = val;
  }

  // Q frags: group 0 starts on tile A, group 1 on tile B
  s16x8 qf0, qf1;
  {
    const int myqt0 = g ? qtB : qtA;
    const u16* qp = Q + qkbase + (size_t)(myqt0 * 64 + rowoff + lr) * DH;
    qf0 = *(const s16x8*)&qp[lq * 8];
    qf1 = *(const s16x8*)&qp[32 + lq * 8];
  }
  f32x4 o[4], os;
#pragma unroll
  for (int t = 0; t < 4; t++) o[t] = (f32x4){0.f, 0.f, 0.f, 0.f};
  os = (f32x4){0.f, 0.f, 0.f, 0.f};

  // staging: 256 thr/group, 2x16B K-chunks + 2x16B V-chunks each
  const int srow = t256 >> 3, soff = (t256 & 7) * 8;   // srow 0..31 (+32 second chunk)
  int kt0 = g ? (16 - bx) : 0;
  s16x8 kr0 = *(const s16x8*)&kgp[(size_t)(kt0 * 64 + srow) * DH + soff];
  s16x8 kr1 = *(const s16x8*)&kgp[(size_t)(kt0 * 64 + srow + 32) * DH + soff];
  s16x8 vr0 = *(const s16x8*)&vtp[(size_t)srow * SEQ + kt0 * 64 + soff];
  s16x8 vr1 = *(const s16x8*)&vtp[(size_t)(srow + 32) * SEQ + kt0 * 64 + soff];

  for (int i = 0; i < 17; ++i) {
    __syncthreads();   // previous iteration's LDS readers done (covers init at i=0)
    *(s16x8*)&Ks[srow * 80 + soff]        = kr0;
    *(s16x8*)&Ks[(srow + 32) * 80 + soff] = kr1;
    *(s16x8*)&Vs[srow * 80 + soff]        = vr0;
    *(s16x8*)&Vs[(srow + 32) * 80 + soff] = vr1;
    __syncthreads();

    // register prefetch of next tile (overlaps compute)
    {
      bool hn = g ? (i + 1 < 16) : (i + 1 < 17);
      if (hn) {
        int ktn = g ? (17 + i - bx) : ((i + 1 <= qtA) ? (i + 1) : (i - qtA));
        kr0 = *(const s16x8*)&kgp[(size_t)(ktn * 64 + srow) * DH + soff];
        kr1 = *(const s16x8*)&kgp[(size_t)(ktn * 64 + srow + 32) * DH + soff];
        vr0 = *(const s16x8*)&vtp[(size_t)srow * SEQ + ktn * 64 + soff];
        vr1 = *(const s16x8*)&vtp[(size_t)(srow + 32) * SEQ + ktn * 64 + soff];
      }
    }

    // group-0 phase transition: tile A complete -> write it, reset acc, switch Q to tile B
    if (g == 0 && i == qtA + 1) {
      float inv[4];
#pragma unroll
      for (int r = 0; r < 4; r++) inv[r] = __builtin_amdgcn_rcpf(__shfl(os[r], lq * 16));
#pragma unroll
      for (int t = 0; t < 4; t++)
#pragma unroll
        for (int r = 0; r < 4; r++) {
          int m = b * SEQ + qtA * 64 + rowoff + lq * 4 + r;
          O[(size_t)m * EMB + hh * 64 + t * 16 + lr] = f2bf(o[t][r] * inv[r]);
        }
#pragma unroll
      for (int t = 0; t < 4; t++) o[t] = (f32x4){0.f, 0.f, 0.f, 0.f};
      os = (f32x4){0.f, 0.f, 0.f, 0.f};
      const u16* qp = Q + qkbase + (size_t)(qtB * 64 + rowoff + lr) * DH;
      qf0 = *(const s16x8*)&qp[lq * 8];
      qf1 = *(const s16x8*)&qp[32 + lq * 8];
    }

    const bool docomp = g ? (i < 16) : true;
    if (docomp) {
      // S = Q @ K^T (16 x 64 per wave); scores in log2 domain (Q pre-scaled)
      f32x4 sc[4];
#pragma unroll
      for (int t = 0; t < 4; t++) {
        s16x8 kf0 = *(const s16x8*)&Ks[(t * 16 + lr) * 80 + lq * 8];
        s16x8 kf1 = *(const s16x8*)&Ks[(t * 16 + lr) * 80 + 32 + lq * 8];
        f32x4 z = (f32x4){0.f, 0.f, 0.f, 0.f};
        z = __builtin_amdgcn_mfma_f32_16x16x32_bf16(qf0, kf0, z, 0, 0, 0);
        z = __builtin_amdgcn_mfma_f32_16x16x32_bf16(qf1, kf1, z, 0, 0, 0);
        sc[t] = z;
      }
      // diagonal mask: group0 hits tile-A diag at i==qtA; group1 hits tile-B diag at i==15
      const bool diag = g ? (i == 15) : (i == qtA);
      if (diag) {
#pragma unroll
        for (int t = 0; t < 4; t++)
#pragma unroll
          for (int r = 0; r < 4; r++)
            if ((t * 16 + lr) > (rowoff + lq * 4 + r)) sc[t][r] = -1e9f;
      }
#pragma unroll
      for (int t = 0; t < 4; t++)
#pragma unroll
        for (int r = 0; r < 4; r++)
          sc[t][r] = __builtin_amdgcn_exp2f(sc[t][r]);

      // P -> per-wave LDS (barrier-free), back as A-operand
#pragma unroll
      for (int t = 0; t < 4; t++)
#pragma unroll
        for (int r = 0; r < 4; r++)
          pw[(lq * 4 + r) * 80 + t * 16 + lr] = f2bf(sc[t][r]);

      // O += P @ V  (+ row-sum via ones-row block)
#pragma unroll
      for (int kc = 0; kc < 2; kc++) {
        s16x8 pf = *(const s16x8*)&pw[lr * 80 + kc * 32 + lq * 8];
#pragma unroll
        for (int t = 0; t < 4; t++) {
          s16x8 vf = *(const s16x8*)&Vs[(t * 16 + lr) * 80 + kc * 32 + lq * 8];
          o[t] = __builtin_amdgcn_mfma_f32_16x16x32_bf16(pf, vf, o[t], 0, 0, 0);
        }
        s16x8 sf = *(const s16x8*)&Vs[(64 + lr) * 80 + kc * 32 + lq * 8];
        os = __builtin_amdgcn_mfma_f32_16x16x32_bf16(pf, sf, os, 0, 0, 0);
      }
    }
  }

  // ---- combine tile B: group 0's partial (fp32) added into group 1's, then write ----
  __syncthreads();
  float* Cb = (float*)smem;             // [64][68] fp32 partials (over group-0 K/V bufs)
  float* Ss = (float*)(smem + 23040);   // 64 partial row-sums (over Ps region)
  if (g == 0) {
#pragma unroll
    for (int t = 0; t < 4; t++)
#pragma unroll
      for (int r = 0; r < 4; r++)
        Cb[(rowoff + lq * 4 + r) * 68 + t * 16 + lr] = o[t][r];
#pragma unroll
    for (int r = 0; r < 4; r++) {
      float s = __shfl(os[r], lq * 16);
      if (lr == 0) Ss[rowoff + lq * 4 + r] = s;
    }
  }
  __syncthreads();
  if (g == 1) {
    float inv[4];
#pragma unroll
    for (int r = 0; r < 4; r++)
      inv[r] = __builtin_amdgcn_rcpf(__shfl(os[r], lq * 16) + Ss[rowoff + lq * 4 + r]);
#pragma unroll
    for (int t = 0; t < 4; t++)
#pragma unroll
      for (int r = 0; r < 4; r++) {
        int m = b * SEQ + qtB * 64 + rowoff + lq * 4 + r;
        float v = o[t][r] + Cb[(rowoff + lq * 4 + r) * 68 + t * 16 + lr];
        O[(size_t)m * EMB + hh * 64 + t * 16 + lr] = f2bf(v * inv[r]);
      }
  }
}

extern "C" void kernel_launch(void* const* d_in, const int* in_sizes, int n_in,
                              void* d_out, int out_size, void* d_ws, size_t ws_size,
                              hipStream_t stream) {
  const float* x  = (const float*)d_in[0];
  const float* Wq = (const float*)d_in[2];
  const float* bq = (const float*)d_in[3];
  const float* Wk = (const float*)d_in[4];
  const float* bk = (const float*)d_in[5];
  const float* Wv = (const float*)d_in[6];
  const float* bv = (const float*)d_in[7];
  const float* Wo = (const float*)d_in[8];
  const float* bo = (const float*)d_in[9];

  char* ws = (char*)d_ws;
  const size_t MB = 1024 * 1024;
  u16* Qb  = (u16*)(ws + 0 * MB);    // [B][H][S][Dh] bf16 (pre-scaled by QSCALE)
  u16* Kb  = (u16*)(ws + 8 * MB);    // [B][H][S][Dh] bf16
  u16* Vtb = (u16*)(ws + 16 * MB);   // [B][H][Dh][S] bf16
  u16* xb  = (u16*)(ws + 24 * MB);   // [M][E] bf16
  u16* Ob  = xb;                     // alias: xb dead after QKV GEMMs
  u16* Wqt = (u16*)(ws + 32 * MB);
  u16* Wkt = (u16*)(ws + 34 * MB);
  u16* Wvt = (u16*)(ws + 36 * MB);
  u16* Wot = (u16*)(ws + 38 * MB);

  cvt_x_kernel<<<(MTOT * EMB) / (256 * 4), 256, 0, stream>>>(x, xb);
  cvt_wt_kernel<<<dim3(EMB / 32, EMB / 32, 4), dim3(32, 8), 0, stream>>>(
      Wq, Wk, Wv, Wo, Wqt, Wkt, Wvt, Wot);

  gemm_qkv<<<dim3(EMB / 64, MTOT / 128, 3), 256, 0, stream>>>(
      xb, Wqt, Wkt, Wvt, bq, bk, bv, Qb, Kb, Vtb);

  attn_fwd<<<dim3(16, NBATCH * HEADS), 512, 0, stream>>>(Qb, Kb, Vtb, Ob);

  gemm_out<<<dim3(EMB / 64, MTOT / 128), 256, 0, stream>>>(Ob, Wot, bo, (float*)d_out);
}